// Round 1
// baseline (6780.096 us; speedup 1.0000x reference)
//
#include <hip/hip_runtime.h>
#include <math.h>

// ---------------------------------------------------------------------------
// KimiDeltaAttention: B=4 T=2048 HID=2048 H=16 DK=DV=128
// Pipeline:
//   1) gemm_nt (fp32, 128x128x8 tiles): q/k/v = silu(h@W.T), fpre=h@f_w0.T,
//      gpre=h@g_w0.T, beta=sigmoid(h@b_w.T)
//   2) gemm_nt: g = kda_gate(fpre@f_w1.T)   (fused -exp(A_log)*softplus(.+dt_bias))
//   3) l2norm on q (scale=DK^-0.5 folded) and k
//   4) kda_scan: per-v-column recurrence, 4 wgs per (b,h), wave-local shfl
//      reductions, double-buffered LDS staging + register prefetch.
//      o written in place over v; final S -> d_out tail.
//   5) gemm_nt: factor = gpre@g_w1.T + g_b1 (reuses g buffer, after scan)
//   6) gate_rmsnorm: o = rms(o)*w*sigmoid(factor)  (in place)
//   7) gemm_nt: out = o @ o_w.T -> d_out
// ---------------------------------------------------------------------------

#define BM 128
#define BN 128
#define BKK 8

enum { ACT_NONE = 0, ACT_SILU = 1, ACT_SIGMOID = 2, ACT_KDAGATE = 3 };

__device__ __forceinline__ float act_apply(float x, int act, int n,
                                           const float* bias, const float* A_log,
                                           const float* dt_bias) {
  if (bias) x += bias[n];
  if (act == ACT_SILU) {
    x = x / (1.f + __expf(-x));
  } else if (act == ACT_SIGMOID) {
    x = 1.f / (1.f + __expf(-x));
  } else if (act == ACT_KDAGATE) {
    float y = x + dt_bias[n];
    float sp = fmaxf(y, 0.f) + log1pf(__expf(-fabsf(y)));
    x = -__expf(A_log[n >> 7]) * sp;
  }
  return x;
}

// C[M,N] = act(A[M,K] @ W[N,K]^T + bias). M%128==0, K%8==0, N%16==0.
__global__ __launch_bounds__(256) void gemm_nt(
    const float* __restrict__ A, const float* __restrict__ W,
    float* __restrict__ C, int M, int N, int K, int act,
    const float* __restrict__ bias, const float* __restrict__ A_log,
    const float* __restrict__ dt_bias) {
  __shared__ alignas(16) float As[BKK][BM + 4];
  __shared__ alignas(16) float Ws[BKK][BN + 4];
  const int tid = threadIdx.x;          // 256
  const int bm = blockIdx.y * BM;
  const int bn = blockIdx.x * BN;
  const int tn = tid & 15, tm = tid >> 4;  // 16x16 threads, 8x8 microtile
  const int lrow = tid >> 1;            // 0..127
  const int lk = (tid & 1) * 4;         // 0 or 4

  float acc[8][8];
#pragma unroll
  for (int i = 0; i < 8; i++)
#pragma unroll
    for (int j = 0; j < 8; j++) acc[i][j] = 0.f;

  for (int k0 = 0; k0 < K; k0 += BKK) {
    const float4 a4 = *(const float4*)&A[(size_t)(bm + lrow) * K + k0 + lk];
    float4 w4 = make_float4(0.f, 0.f, 0.f, 0.f);
    if (bn + lrow < N) w4 = *(const float4*)&W[(size_t)(bn + lrow) * K + k0 + lk];
    __syncthreads();  // previous iteration's reads complete
    As[lk + 0][lrow] = a4.x; As[lk + 1][lrow] = a4.y;
    As[lk + 2][lrow] = a4.z; As[lk + 3][lrow] = a4.w;
    Ws[lk + 0][lrow] = w4.x; Ws[lk + 1][lrow] = w4.y;
    Ws[lk + 2][lrow] = w4.z; Ws[lk + 3][lrow] = w4.w;
    __syncthreads();
#pragma unroll
    for (int kk = 0; kk < BKK; kk++) {
      const float4 a0 = *(const float4*)&As[kk][tm * 8];
      const float4 a1 = *(const float4*)&As[kk][tm * 8 + 4];
      const float4 b0 = *(const float4*)&Ws[kk][tn * 8];
      const float4 b1 = *(const float4*)&Ws[kk][tn * 8 + 4];
      const float av[8] = {a0.x, a0.y, a0.z, a0.w, a1.x, a1.y, a1.z, a1.w};
      const float bv[8] = {b0.x, b0.y, b0.z, b0.w, b1.x, b1.y, b1.z, b1.w};
#pragma unroll
      for (int i = 0; i < 8; i++)
#pragma unroll
        for (int j = 0; j < 8; j++) acc[i][j] = fmaf(av[i], bv[j], acc[i][j]);
    }
  }
#pragma unroll
  for (int i = 0; i < 8; i++) {
    const int m = bm + tm * 8 + i;
#pragma unroll
    for (int j4 = 0; j4 < 8; j4 += 4) {
      const int n = bn + tn * 8 + j4;
      if (n < N) {
        float4 r;
        r.x = act_apply(acc[i][j4 + 0], act, n + 0, bias, A_log, dt_bias);
        r.y = act_apply(acc[i][j4 + 1], act, n + 1, bias, A_log, dt_bias);
        r.z = act_apply(acc[i][j4 + 2], act, n + 2, bias, A_log, dt_bias);
        r.w = act_apply(acc[i][j4 + 3], act, n + 3, bias, A_log, dt_bias);
        *(float4*)&C[(size_t)m * N + n] = r;
      }
    }
  }
}

// In-place l2norm over contiguous 128-element rows; q-scale folded in.
__global__ __launch_bounds__(64) void l2norm_k(float* __restrict__ x, float scale) {
  const size_t base = (size_t)blockIdx.x * 128;
  const int lane = threadIdx.x;
  const float a = x[base + lane];
  const float b = x[base + lane + 64];
  float ss = fmaf(a, a, b * b);
#pragma unroll
  for (int m = 1; m < 64; m <<= 1) ss += __shfl_xor(ss, m);
  const float r = rsqrtf(ss + 1e-6f) * scale;
  x[base + lane] = a * r;
  x[base + lane + 64] = b * r;
}

// Gated delta-rule scan. grid = B*H*4; block = 256 (4 waves x 8 columns x 8 kgroups).
// o aliases v (no __restrict__ on those): o[t] written after v[t+1] prefetched,
// disjoint rows, ordered by the per-step barrier.
__global__ __launch_bounds__(256) void kda_scan(
    const float* __restrict__ q, const float* __restrict__ k,
    const float* v, const float* __restrict__ g,
    const float* __restrict__ beta, const float* __restrict__ S0,
    float* o, float* __restrict__ S_out) {
  const int bid = blockIdx.x;  // 256 = B*H*4
  const int quarter = bid & 3;
  const int bh = bid >> 2;
  const int h = bh & 15;
  const int b = bh >> 4;
  const int tid = threadIdx.x;
  const int lane = tid & 63;
  const int wave = tid >> 6;
  const int vloc = quarter * 32 + wave * 8 + (lane & 7);  // column in [0,128)
  const int kg = lane >> 3;   // 8 k-groups of 16
  const int k0 = kg * 16;

  __shared__ alignas(16) float kb[2][128];
  __shared__ alignas(16) float qb[2][128];
  __shared__ alignas(16) float gb[2][128];
  __shared__ float vb[2][32];
  __shared__ float betab[2];

  float S[16];
  const size_t s_base = (size_t)(b * 16 + h) * 128 * 128;
#pragma unroll
  for (int j = 0; j < 16; j++) S[j] = S0[s_base + (size_t)(k0 + j) * 128 + vloc];

  const size_t rowbase = (size_t)b * 2048 * 2048 + (size_t)h * 128;
  float kr = 0.f, qr = 0.f, gr = 0.f, vr = 0.f, br = 0.f;
  if (tid < 128) {
    kr = k[rowbase + tid]; qr = q[rowbase + tid]; gr = g[rowbase + tid];
  } else if (tid < 160) {
    vr = v[rowbase + quarter * 32 + (tid - 128)];
  } else if (tid == 160) {
    br = beta[(size_t)(b * 2048) * 16 + h];
  }

  for (int t = 0; t < 2048; t++) {
    const int buf = t & 1;
    if (tid < 128) {
      kb[buf][tid] = kr; qb[buf][tid] = qr; gb[buf][tid] = __expf(gr);
    } else if (tid < 160) {
      vb[buf][tid - 128] = vr;
    } else if (tid == 160) {
      betab[buf] = br;
    }
    if (t + 1 < 2048) {  // register prefetch of next step (hides global latency)
      const size_t a = rowbase + (size_t)(t + 1) * 2048;
      if (tid < 128) {
        kr = k[a + tid]; qr = q[a + tid]; gr = g[a + tid];
      } else if (tid < 160) {
        vr = v[a + quarter * 32 + (tid - 128)];
      } else if (tid == 160) {
        br = beta[((size_t)(b * 2048 + t + 1)) * 16 + h];
      }
    }
    __syncthreads();

    // decay + k.S partial
    float p = 0.f;
#pragma unroll
    for (int jj = 0; jj < 16; jj += 4) {
      const float4 ge = *(const float4*)&gb[buf][k0 + jj];
      const float4 kk = *(const float4*)&kb[buf][k0 + jj];
      S[jj + 0] *= ge.x; p = fmaf(kk.x, S[jj + 0], p);
      S[jj + 1] *= ge.y; p = fmaf(kk.y, S[jj + 1], p);
      S[jj + 2] *= ge.z; p = fmaf(kk.z, S[jj + 2], p);
      S[jj + 3] *= ge.w; p = fmaf(kk.w, S[jj + 3], p);
    }
    p += __shfl_xor(p, 8);
    p += __shfl_xor(p, 16);
    p += __shfl_xor(p, 32);
    const float delta = (vb[buf][vloc & 31] - p) * betab[buf];

    // rank-1 update + q.S partial
    float op = 0.f;
#pragma unroll
    for (int jj = 0; jj < 16; jj += 4) {
      const float4 kk = *(const float4*)&kb[buf][k0 + jj];
      const float4 qq = *(const float4*)&qb[buf][k0 + jj];
      S[jj + 0] = fmaf(kk.x, delta, S[jj + 0]); op = fmaf(qq.x, S[jj + 0], op);
      S[jj + 1] = fmaf(kk.y, delta, S[jj + 1]); op = fmaf(qq.y, S[jj + 1], op);
      S[jj + 2] = fmaf(kk.z, delta, S[jj + 2]); op = fmaf(qq.z, S[jj + 2], op);
      S[jj + 3] = fmaf(kk.w, delta, S[jj + 3]); op = fmaf(qq.w, S[jj + 3], op);
    }
    op += __shfl_xor(op, 8);
    op += __shfl_xor(op, 16);
    op += __shfl_xor(op, 32);
    if (kg == 0) o[rowbase + (size_t)t * 2048 + vloc] = op;
  }
#pragma unroll
  for (int j = 0; j < 16; j++)
    S_out[s_base + (size_t)(k0 + j) * 128 + vloc] = S[j];
}

// o = o * rsqrt(mean(o^2)+1e-5) * w * sigmoid(factor), per (m,h) row of 128.
__global__ __launch_bounds__(128) void gate_rmsnorm(
    float* o, const float* __restrict__ factor, const float* __restrict__ w) {
  const size_t base = (size_t)blockIdx.x * 128;
  const int vi = threadIdx.x;
  const float x = o[base + vi];
  float ss = x * x;
#pragma unroll
  for (int m = 1; m < 64; m <<= 1) ss += __shfl_xor(ss, m);
  __shared__ float red[2];
  if ((vi & 63) == 0) red[vi >> 6] = ss;
  __syncthreads();
  const float tot = red[0] + red[1];
  const float r = rsqrtf(tot * (1.f / 128.f) + 1e-5f);
  const float f = factor[base + vi];
  const float sig = 1.f / (1.f + __expf(-f));
  o[base + vi] = x * r * w[vi] * sig;
}

extern "C" void kernel_launch(void* const* d_in, const int* in_sizes, int n_in,
                              void* d_out, int out_size, void* d_ws, size_t ws_size,
                              hipStream_t stream) {
  const float* h    = (const float*)d_in[0];
  const float* S0   = (const float*)d_in[1];
  const float* q_w  = (const float*)d_in[2];
  const float* k_w  = (const float*)d_in[3];
  const float* v_w  = (const float*)d_in[4];
  const float* f_w0 = (const float*)d_in[5];
  const float* f_w1 = (const float*)d_in[6];
  const float* b_w  = (const float*)d_in[7];
  const float* A_log  = (const float*)d_in[8];
  const float* dt_b   = (const float*)d_in[9];
  const float* g_w0 = (const float*)d_in[10];
  const float* g_w1 = (const float*)d_in[11];
  const float* g_b1 = (const float*)d_in[12];
  const float* o_nw = (const float*)d_in[13];
  const float* o_w  = (const float*)d_in[14];

  float* outp = (float*)d_out;                       // [8192,2048]
  float* Sout = outp + (size_t)8192 * 2048;          // [4,16,128,128]

  float* ws = (float*)d_ws;
  const size_t BIG = (size_t)8192 * 2048;
  float* qb   = ws;
  float* kb   = ws + BIG;
  float* vb   = ws + 2 * BIG;   // v -> o -> gated o (in place)
  float* gbuf = ws + 3 * BIG;   // g -> (after scan) factor
  float* fpre = ws + 4 * BIG;
  float* gpre = fpre + (size_t)8192 * 128;
  float* betab = gpre + (size_t)8192 * 128;

  const dim3 blk(256);
  const dim3 gbig(2048 / BN, 8192 / BM);  // (16,64)
  const dim3 gnarrow(1, 8192 / BM);

  // projections
  gemm_nt<<<gbig, blk, 0, stream>>>(h, q_w, qb, 8192, 2048, 2048, ACT_SILU, nullptr, nullptr, nullptr);
  gemm_nt<<<gbig, blk, 0, stream>>>(h, k_w, kb, 8192, 2048, 2048, ACT_SILU, nullptr, nullptr, nullptr);
  gemm_nt<<<gbig, blk, 0, stream>>>(h, v_w, vb, 8192, 2048, 2048, ACT_SILU, nullptr, nullptr, nullptr);
  gemm_nt<<<gnarrow, blk, 0, stream>>>(h, f_w0, fpre, 8192, 128, 2048, ACT_NONE, nullptr, nullptr, nullptr);
  gemm_nt<<<gnarrow, blk, 0, stream>>>(h, g_w0, gpre, 8192, 128, 2048, ACT_NONE, nullptr, nullptr, nullptr);
  gemm_nt<<<gnarrow, blk, 0, stream>>>(h, b_w, betab, 8192, 16, 2048, ACT_SIGMOID, nullptr, nullptr, nullptr);
  // g = kda_gate(fpre @ f_w1.T)
  gemm_nt<<<gbig, blk, 0, stream>>>(fpre, f_w1, gbuf, 8192, 2048, 128, ACT_KDAGATE, nullptr, A_log, dt_b);
  // l2norm (q gets DK^-0.5 folded in)
  l2norm_k<<<131072, 64, 0, stream>>>(qb, 0.08838834764831845f);
  l2norm_k<<<131072, 64, 0, stream>>>(kb, 1.0f);
  // recurrence: o over vb in place, S -> d_out tail
  kda_scan<<<256, 256, 0, stream>>>(qb, kb, vb, gbuf, betab, S0, vb, Sout);
  // factor = gpre @ g_w1.T + g_b1 (g buffer is dead after the scan)
  gemm_nt<<<gbig, blk, 0, stream>>>(gpre, g_w1, gbuf, 8192, 2048, 128, ACT_NONE, g_b1, nullptr, nullptr);
  // gated rmsnorm in place
  gate_rmsnorm<<<131072, 128, 0, stream>>>(vb, gbuf, o_nw);
  // output projection
  gemm_nt<<<gbig, blk, 0, stream>>>(vb, o_w, outp, 8192, 2048, 2048, ACT_NONE, nullptr, nullptr, nullptr);
}

// Round 2
// 2727.349 us; speedup vs baseline: 2.4860x; 2.4860x over previous
//
#include <hip/hip_runtime.h>
#include <math.h>

// ---------------------------------------------------------------------------
// KimiDeltaAttention B=4 T=2048 HID=2048 H=16 DK=DV=128
//  - bf16 MFMA GEMMs (m97 structure: global_load_lds w=16, XOR-swizzled LDS,
//    16x16x32 bf16, 128x128 tile, 4 waves, 4x4 frags)
//  - barrier-free scan: 2048 single-wave blocks, 4 cols x 16-way ksplit,
//    register prefetch, shfl reductions; exp(g) precomputed in gate epilogue
// ---------------------------------------------------------------------------

typedef short short8 __attribute__((ext_vector_type(8)));
typedef float f32x4 __attribute__((ext_vector_type(4)));
typedef unsigned short ushort_t;

enum { ACT_NONE = 0, ACT_SILU = 1, ACT_SIGMOID = 2, ACT_KDAGATE_EXP = 3 };

__device__ __forceinline__ unsigned short f32_to_bf16(float f) {
  unsigned int u = __float_as_uint(f);
  u += 0x7FFFu + ((u >> 16) & 1u);   // RNE
  return (unsigned short)(u >> 16);
}

__device__ __forceinline__ float epi_act(float x, int act, int n,
                                         const float* bias, const float* A_log,
                                         const float* dt_bias) {
  if (bias) x += bias[n];
  if (act == ACT_SILU) {
    x = x / (1.f + __expf(-x));
  } else if (act == ACT_SIGMOID) {
    x = 1.f / (1.f + __expf(-x));
  } else if (act == ACT_KDAGATE_EXP) {
    float y = x + dt_bias[n];
    float sp = fmaxf(y, 0.f) + log1pf(__expf(-fabsf(y)));
    x = __expf(-__expf(A_log[n >> 7]) * sp);   // exp(g): scan decay factor
  }
  return x;
}

__device__ __forceinline__ void gld_lds16(const void* g, void* l) {
  __builtin_amdgcn_global_load_lds(
      (const __attribute__((address_space(1))) unsigned int*)g,
      (__attribute__((address_space(3))) unsigned int*)l, 16, 0, 0);
}

// C[M,N] = act(A[M,K] @ W[N,K]^T). bf16 in, fp32 or bf16 out.
// M%128==0, N%128==0, K%32==0.
__global__ __launch_bounds__(256) void gemm_bf16_nt(
    const ushort_t* __restrict__ A, const ushort_t* __restrict__ W,
    float* __restrict__ Cf, ushort_t* __restrict__ Cb,
    int M, int N, int K, int act, const float* __restrict__ bias,
    const float* __restrict__ A_log, const float* __restrict__ dt_bias) {
  __shared__ alignas(16) ushort_t As[4096];  // [128 rows][32 k] bf16, 8KB
  __shared__ alignas(16) ushort_t Bs[4096];
  const int tid = threadIdx.x;
  const int wv = tid >> 6, ln = tid & 63;
  const int bm = blockIdx.y * 128, bn = blockIdx.x * 128;
  const int wm = wv >> 1, wn = wv & 1;

  // staging: chunk c = inst*256 + tid -> row=c>>2, physgrp=c&3,
  // logical kgrp = physgrp ^ ((row>>1)&3)   (XOR swizzle kills bank conflicts)
  const int srow = tid >> 2;
  const int skg = (tid & 3) ^ ((srow >> 1) & 3);
  const size_t ag0 = (size_t)(bm + srow) * K + skg * 8;
  const size_t ag1 = ag0 + (size_t)64 * K;
  const size_t bg0 = (size_t)(bn + srow) * K + skg * 8;
  const size_t bg1 = bg0 + (size_t)64 * K;
  char* const lA = (char*)As;
  char* const lB = (char*)Bs;
  const int wbase = wv * 1024;   // wave-uniform LDS dest

  // fragment read offsets: lane holds X[r = ln&15][k = (ln>>4)*8 + j]
  const int fr = ln & 15, fq = ln >> 4;
  const int pg = fq ^ ((fr >> 1) & 3);
  int aoff[4], boff[4];
#pragma unroll
  for (int i = 0; i < 4; i++) {
    aoff[i] = (wm * 64 + i * 16 + fr) * 64 + pg * 16;
    boff[i] = (wn * 64 + i * 16 + fr) * 64 + pg * 16;
  }

  f32x4 acc[4][4];
#pragma unroll
  for (int i = 0; i < 4; i++)
#pragma unroll
    for (int j = 0; j < 4; j++) {
      acc[i][j][0] = 0.f; acc[i][j][1] = 0.f; acc[i][j][2] = 0.f; acc[i][j][3] = 0.f;
    }

  for (int k0 = 0; k0 < K; k0 += 32) {
    gld_lds16(A + ag0 + k0, lA + wbase);
    gld_lds16(A + ag1 + k0, lA + 4096 + wbase);
    gld_lds16(W + bg0 + k0, lB + wbase);
    gld_lds16(W + bg1 + k0, lB + 4096 + wbase);
    __syncthreads();
    short8 af[4], bf[4];
#pragma unroll
    for (int i = 0; i < 4; i++) af[i] = *(const short8*)(lA + aoff[i]);
#pragma unroll
    for (int i = 0; i < 4; i++) bf[i] = *(const short8*)(lB + boff[i]);
#pragma unroll
    for (int i = 0; i < 4; i++)
#pragma unroll
      for (int j = 0; j < 4; j++)
        acc[i][j] = __builtin_amdgcn_mfma_f32_16x16x32_bf16(af[i], bf[j], acc[i][j], 0, 0, 0);
    __syncthreads();
  }

  // C/D layout: col = ln&15, row = (ln>>4)*4 + reg  [m89-verified]
  const int cc = ln & 15, cq = ln >> 4;
#pragma unroll
  for (int i = 0; i < 4; i++) {
#pragma unroll
    for (int r = 0; r < 4; r++) {
      const int gm = bm + wm * 64 + i * 16 + cq * 4 + r;
#pragma unroll
      for (int j = 0; j < 4; j++) {
        const int gn = bn + wn * 64 + j * 16 + cc;
        float x = epi_act(acc[i][j][r], act, gn, bias, A_log, dt_bias);
        if (Cb) Cb[(size_t)gm * N + gn] = f32_to_bf16(x);
        else    Cf[(size_t)gm * N + gn] = x;
      }
    }
  }
}

// fp32 fallback GEMM (beta projection, N=16). 128x128x8 tiles.
#define BM 128
#define BN 128
#define BKK 8
__global__ __launch_bounds__(256) void gemm_nt(
    const float* __restrict__ A, const float* __restrict__ W,
    float* __restrict__ C, int M, int N, int K, int act) {
  __shared__ alignas(16) float Asf[BKK][BM + 4];
  __shared__ alignas(16) float Wsf[BKK][BN + 4];
  const int tid = threadIdx.x;
  const int bm = blockIdx.y * BM;
  const int bn = blockIdx.x * BN;
  const int tn = tid & 15, tm = tid >> 4;
  const int lrow = tid >> 1;
  const int lk = (tid & 1) * 4;

  float acc[8][8];
#pragma unroll
  for (int i = 0; i < 8; i++)
#pragma unroll
    for (int j = 0; j < 8; j++) acc[i][j] = 0.f;

  for (int k0 = 0; k0 < K; k0 += BKK) {
    const float4 a4 = *(const float4*)&A[(size_t)(bm + lrow) * K + k0 + lk];
    float4 w4 = make_float4(0.f, 0.f, 0.f, 0.f);
    if (bn + lrow < N) w4 = *(const float4*)&W[(size_t)(bn + lrow) * K + k0 + lk];
    __syncthreads();
    Asf[lk + 0][lrow] = a4.x; Asf[lk + 1][lrow] = a4.y;
    Asf[lk + 2][lrow] = a4.z; Asf[lk + 3][lrow] = a4.w;
    Wsf[lk + 0][lrow] = w4.x; Wsf[lk + 1][lrow] = w4.y;
    Wsf[lk + 2][lrow] = w4.z; Wsf[lk + 3][lrow] = w4.w;
    __syncthreads();
#pragma unroll
    for (int kk = 0; kk < BKK; kk++) {
      const float4 a0 = *(const float4*)&Asf[kk][tm * 8];
      const float4 a1 = *(const float4*)&Asf[kk][tm * 8 + 4];
      const float4 b0 = *(const float4*)&Wsf[kk][tn * 8];
      const float4 b1 = *(const float4*)&Wsf[kk][tn * 8 + 4];
      const float av[8] = {a0.x, a0.y, a0.z, a0.w, a1.x, a1.y, a1.z, a1.w};
      const float bv[8] = {b0.x, b0.y, b0.z, b0.w, b1.x, b1.y, b1.z, b1.w};
#pragma unroll
      for (int i = 0; i < 8; i++)
#pragma unroll
        for (int j = 0; j < 8; j++) acc[i][j] = fmaf(av[i], bv[j], acc[i][j]);
    }
  }
#pragma unroll
  for (int i = 0; i < 8; i++) {
    const int m = bm + tm * 8 + i;
#pragma unroll
    for (int j = 0; j < 8; j++) {
      const int n = bn + tn * 8 + j;
      if (n < N) {
        float x = acc[i][j];
        if (act == ACT_SIGMOID) x = 1.f / (1.f + __expf(-x));
        C[(size_t)m * N + n] = x;
      }
    }
  }
}

__global__ __launch_bounds__(256) void cast_bf16(const float* __restrict__ x,
                                                 ushort_t* __restrict__ y, int n) {
  const int i = (blockIdx.x * 256 + threadIdx.x) * 4;
  if (i >= n) return;
  const float4 v = *(const float4*)&x[i];
  union { ushort_t u[4]; uint2 v2; } o;
  o.u[0] = f32_to_bf16(v.x); o.u[1] = f32_to_bf16(v.y);
  o.u[2] = f32_to_bf16(v.z); o.u[3] = f32_to_bf16(v.w);
  *(uint2*)&y[i] = o.v2;
}

__global__ __launch_bounds__(64) void l2norm_k(float* __restrict__ x, float scale) {
  const size_t base = (size_t)blockIdx.x * 128;
  const int lane = threadIdx.x;
  const float a = x[base + lane];
  const float b = x[base + lane + 64];
  float ss = fmaf(a, a, b * b);
#pragma unroll
  for (int m = 1; m < 64; m <<= 1) ss += __shfl_xor(ss, m);
  const float r = rsqrtf(ss + 1e-6f) * scale;
  x[base + lane] = a * r;
  x[base + lane + 64] = b * r;
}

// Barrier-free gated delta-rule scan.
// grid = 2048 (64 bh x 32 colgroups, XCD-swizzled), block = 64 (one wave).
// Lane = (cl = ln>>4) in 0..3 columns x (kg = ln&15) 16-way k-split, S[8]/lane.
// ge = exp(g) precomputed. o aliases v (same rows, write-after-consume).
__global__ __launch_bounds__(64) void kda_scan(
    const float* __restrict__ q, const float* __restrict__ k,
    const float* v, const float* __restrict__ ge,
    const float* __restrict__ beta, const float* __restrict__ S0,
    float* o, float* __restrict__ S_out) {
  const int bid = blockIdx.x;
  const int bh = (((bid >> 3) & 7) << 3) | (bid & 7);  // same-bh blocks -> same XCD
  const int cg = bid >> 6;
  const int h = bh & 15, b = bh >> 4;
  const int ln = threadIdx.x;
  const int cl = ln >> 4, kg = ln & 15;
  const int col = cg * 4 + cl;
  const int kof = kg * 8;

  const size_t s_base = (size_t)bh * (128 * 128);
  float S[8];
#pragma unroll
  for (int j = 0; j < 8; j++) S[j] = S0[s_base + (size_t)(kof + j) * 128 + col];

  const size_t rowbase = (size_t)b * (2048 * 2048) + (size_t)h * 128;
  const size_t bbase = (size_t)(b * 2048) * 16 + h;

  float4 kc0 = *(const float4*)&k[rowbase + kof];
  float4 kc1 = *(const float4*)&k[rowbase + kof + 4];
  float4 qc0 = *(const float4*)&q[rowbase + kof];
  float4 qc1 = *(const float4*)&q[rowbase + kof + 4];
  float4 gc0 = *(const float4*)&ge[rowbase + kof];
  float4 gc1 = *(const float4*)&ge[rowbase + kof + 4];
  float vc = v[rowbase + col];
  float bc = beta[bbase];

  for (int t = 0; t < 2048; t++) {
    const int tn = (t < 2047) ? t + 1 : 2047;
    const size_t a = rowbase + (size_t)tn * 2048;
    const float4 kn0 = *(const float4*)&k[a + kof];
    const float4 kn1 = *(const float4*)&k[a + kof + 4];
    const float4 qn0 = *(const float4*)&q[a + kof];
    const float4 qn1 = *(const float4*)&q[a + kof + 4];
    const float4 gn0 = *(const float4*)&ge[a + kof];
    const float4 gn1 = *(const float4*)&ge[a + kof + 4];
    const float vn = v[a + col];
    const float bn = beta[bbase + (size_t)tn * 16];

    float p = 0.f;
    S[0] *= gc0.x; p = fmaf(kc0.x, S[0], p);
    S[1] *= gc0.y; p = fmaf(kc0.y, S[1], p);
    S[2] *= gc0.z; p = fmaf(kc0.z, S[2], p);
    S[3] *= gc0.w; p = fmaf(kc0.w, S[3], p);
    S[4] *= gc1.x; p = fmaf(kc1.x, S[4], p);
    S[5] *= gc1.y; p = fmaf(kc1.y, S[5], p);
    S[6] *= gc1.z; p = fmaf(kc1.z, S[6], p);
    S[7] *= gc1.w; p = fmaf(kc1.w, S[7], p);
    p += __shfl_xor(p, 1); p += __shfl_xor(p, 2);
    p += __shfl_xor(p, 4); p += __shfl_xor(p, 8);
    const float delta = (vc - p) * bc;

    float op = 0.f;
    S[0] = fmaf(kc0.x, delta, S[0]); op = fmaf(qc0.x, S[0], op);
    S[1] = fmaf(kc0.y, delta, S[1]); op = fmaf(qc0.y, S[1], op);
    S[2] = fmaf(kc0.z, delta, S[2]); op = fmaf(qc0.z, S[2], op);
    S[3] = fmaf(kc0.w, delta, S[3]); op = fmaf(qc0.w, S[3], op);
    S[4] = fmaf(kc1.x, delta, S[4]); op = fmaf(qc1.x, S[4], op);
    S[5] = fmaf(kc1.y, delta, S[5]); op = fmaf(qc1.y, S[5], op);
    S[6] = fmaf(kc1.z, delta, S[6]); op = fmaf(qc1.z, S[6], op);
    S[7] = fmaf(kc1.w, delta, S[7]); op = fmaf(qc1.w, S[7], op);
    op += __shfl_xor(op, 1); op += __shfl_xor(op, 2);
    op += __shfl_xor(op, 4); op += __shfl_xor(op, 8);
    if (kg == 0) o[rowbase + (size_t)t * 2048 + col] = op;

    kc0 = kn0; kc1 = kn1; qc0 = qn0; qc1 = qn1; gc0 = gn0; gc1 = gn1;
    vc = vn; bc = bn;
  }
#pragma unroll
  for (int j = 0; j < 8; j++)
    S_out[s_base + (size_t)(kof + j) * 128 + col] = S[j];
}

// out_bf16 = rms(o)*w*sigmoid(factor)
__global__ __launch_bounds__(128) void gate_rmsnorm(
    const float* __restrict__ o, const float* __restrict__ factor,
    const float* __restrict__ w, ushort_t* __restrict__ out) {
  const size_t base = (size_t)blockIdx.x * 128;
  const int vi = threadIdx.x;
  const float x = o[base + vi];
  float ss = x * x;
#pragma unroll
  for (int m = 1; m < 64; m <<= 1) ss += __shfl_xor(ss, m);
  __shared__ float red[2];
  if ((vi & 63) == 0) red[vi >> 6] = ss;
  __syncthreads();
  const float tot = red[0] + red[1];
  const float r = rsqrtf(tot * (1.f / 128.f) + 1e-5f);
  const float f = factor[base + vi];
  const float sig = 1.f / (1.f + __expf(-f));
  out[base + vi] = f32_to_bf16(x * r * w[vi] * sig);
}

extern "C" void kernel_launch(void* const* d_in, const int* in_sizes, int n_in,
                              void* d_out, int out_size, void* d_ws, size_t ws_size,
                              hipStream_t stream) {
  const float* h    = (const float*)d_in[0];
  const float* S0   = (const float*)d_in[1];
  const float* q_w  = (const float*)d_in[2];
  const float* k_w  = (const float*)d_in[3];
  const float* v_w  = (const float*)d_in[4];
  const float* f_w0 = (const float*)d_in[5];
  const float* f_w1 = (const float*)d_in[6];
  const float* b_w  = (const float*)d_in[7];
  const float* A_log  = (const float*)d_in[8];
  const float* dt_b   = (const float*)d_in[9];
  const float* g_w0 = (const float*)d_in[10];
  const float* g_w1 = (const float*)d_in[11];
  const float* g_b1 = (const float*)d_in[12];
  const float* o_nw = (const float*)d_in[13];
  const float* o_w  = (const float*)d_in[14];

  float* outp = (float*)d_out;                 // [8192,2048] (also exp(g)/factor scratch)
  float* Sout = outp + (size_t)8192 * 2048;    // [4,16,128,128]
  float* gbuf = outp;                          // exp(g), then factor — both pre-final

  const size_t BIG = (size_t)8192 * 2048;
  float* ws = (float*)d_ws;
  float* qb    = ws;
  float* kbuf  = qb + BIG;
  float* vbuf  = kbuf + BIG;
  float* betab = vbuf + BIG;                           // 8192*16
  ushort_t* hb  = (ushort_t*)(betab + (size_t)8192 * 16);  // bf16 h / later bf16 gated o
  ushort_t* wq  = hb + BIG;
  ushort_t* wk  = wq + (size_t)2048 * 2048;
  ushort_t* wv  = wk + (size_t)2048 * 2048;
  ushort_t* wo  = wv + (size_t)2048 * 2048;
  ushort_t* wf0 = wo + (size_t)2048 * 2048;
  ushort_t* wg0 = wf0 + (size_t)128 * 2048;
  ushort_t* wf1 = wg0 + (size_t)128 * 2048;
  ushort_t* wg1 = wf1 + (size_t)2048 * 128;
  ushort_t* fpreb = wg1 + (size_t)2048 * 128;          // [8192,128] bf16
  ushort_t* gpreb = fpreb + (size_t)8192 * 128;

  const dim3 blk(256);
  const dim3 gbig(16, 64);
  const dim3 gnarrow(1, 64);

  // casts
  cast_bf16<<<16384, blk, 0, stream>>>(h, hb, 8192 * 2048);
  cast_bf16<<<4096, blk, 0, stream>>>(q_w, wq, 2048 * 2048);
  cast_bf16<<<4096, blk, 0, stream>>>(k_w, wk, 2048 * 2048);
  cast_bf16<<<4096, blk, 0, stream>>>(v_w, wv, 2048 * 2048);
  cast_bf16<<<4096, blk, 0, stream>>>(o_w, wo, 2048 * 2048);
  cast_bf16<<<256, blk, 0, stream>>>(f_w0, wf0, 128 * 2048);
  cast_bf16<<<256, blk, 0, stream>>>(g_w0, wg0, 128 * 2048);
  cast_bf16<<<256, blk, 0, stream>>>(f_w1, wf1, 2048 * 128);
  cast_bf16<<<256, blk, 0, stream>>>(g_w1, wg1, 2048 * 128);

  // projections (bf16 MFMA)
  gemm_bf16_nt<<<gbig, blk, 0, stream>>>(hb, wq, qb, nullptr, 8192, 2048, 2048, ACT_SILU, nullptr, nullptr, nullptr);
  gemm_bf16_nt<<<gbig, blk, 0, stream>>>(hb, wk, kbuf, nullptr, 8192, 2048, 2048, ACT_SILU, nullptr, nullptr, nullptr);
  gemm_bf16_nt<<<gbig, blk, 0, stream>>>(hb, wv, vbuf, nullptr, 8192, 2048, 2048, ACT_SILU, nullptr, nullptr, nullptr);
  gemm_bf16_nt<<<gnarrow, blk, 0, stream>>>(hb, wf0, nullptr, fpreb, 8192, 128, 2048, ACT_NONE, nullptr, nullptr, nullptr);
  gemm_bf16_nt<<<gnarrow, blk, 0, stream>>>(hb, wg0, nullptr, gpreb, 8192, 128, 2048, ACT_NONE, nullptr, nullptr, nullptr);
  gemm_nt<<<gnarrow, blk, 0, stream>>>(h, b_w, betab, 8192, 16, 2048, ACT_SIGMOID);
  // exp(g) = exp(-exp(A_log)*softplus(fpre@f_w1.T + dt_bias)) -> gbuf(=outp)
  gemm_bf16_nt<<<gbig, blk, 0, stream>>>(fpreb, wf1, gbuf, nullptr, 8192, 2048, 128, ACT_KDAGATE_EXP, nullptr, A_log, dt_b);
  // l2norm (q gets DK^-0.5 folded)
  l2norm_k<<<131072, 64, 0, stream>>>(qb, 0.08838834764831845f);
  l2norm_k<<<131072, 64, 0, stream>>>(kbuf, 1.0f);
  // scan: o in place over vbuf, S -> d_out tail
  kda_scan<<<2048, 64, 0, stream>>>(qb, kbuf, vbuf, gbuf, betab, S0, vbuf, Sout);
  // factor = gpre @ g_w1.T + g_b1 -> outp (gbuf region dead after scan)
  gemm_bf16_nt<<<gbig, blk, 0, stream>>>(gpreb, wg1, gbuf, nullptr, 8192, 2048, 128, ACT_NONE, g_b1, nullptr, nullptr);
  // gated rmsnorm -> bf16 (reuses hb)
  gate_rmsnorm<<<131072, 128, 0, stream>>>(vbuf, gbuf, o_nw, hb);
  // out = o @ o_w.T
  gemm_bf16_nt<<<gbig, blk, 0, stream>>>(hb, wo, outp, nullptr, 8192, 2048, 2048, ACT_NONE, nullptr, nullptr, nullptr);
}

// Round 3
// 2130.478 us; speedup vs baseline: 3.1824x; 1.2802x over previous
//
#include <hip/hip_runtime.h>
#include <math.h>

// ---------------------------------------------------------------------------
// KimiDeltaAttention B=4 T=2048 HID=2048 H=16 DK=DV=128
//  - bf16 MFMA GEMMs (m97 structure)
//  - scan v3: no aliasing (separate o buffer, all __restrict__), bf16 q/k,
//    DPP 16-lane reductions (no ds_swizzle in the carried chain),
//    4-slot rotating register prefetch (depth ~3 steps).
// ---------------------------------------------------------------------------

typedef short short8 __attribute__((ext_vector_type(8)));
typedef float f32x4 __attribute__((ext_vector_type(4)));
typedef unsigned short ushort_t;

enum { ACT_NONE = 0, ACT_SILU = 1, ACT_SIGMOID = 2, ACT_KDAGATE_EXP = 3 };

__device__ __forceinline__ unsigned short f32_to_bf16(float f) {
  unsigned int u = __float_as_uint(f);
  u += 0x7FFFu + ((u >> 16) & 1u);   // RNE
  return (unsigned short)(u >> 16);
}

__device__ __forceinline__ float epi_act(float x, int act, int n,
                                         const float* bias, const float* A_log,
                                         const float* dt_bias) {
  if (bias) x += bias[n];
  if (act == ACT_SILU) {
    x = x / (1.f + __expf(-x));
  } else if (act == ACT_SIGMOID) {
    x = 1.f / (1.f + __expf(-x));
  } else if (act == ACT_KDAGATE_EXP) {
    float y = x + dt_bias[n];
    float sp = fmaxf(y, 0.f) + log1pf(__expf(-fabsf(y)));
    x = __expf(-__expf(A_log[n >> 7]) * sp);   // exp(g): scan decay factor
  }
  return x;
}

__device__ __forceinline__ void gld_lds16(const void* g, void* l) {
  __builtin_amdgcn_global_load_lds(
      (const __attribute__((address_space(1))) unsigned int*)g,
      (__attribute__((address_space(3))) unsigned int*)l, 16, 0, 0);
}

// sum across each aligned 16-lane group, pure DPP (no LDS pipe)
__device__ __forceinline__ float row16_sum(float x) {
  x += __int_as_float(__builtin_amdgcn_update_dpp(0, __float_as_int(x), 0xB1, 0xF, 0xF, true));  // quad_perm xor1
  x += __int_as_float(__builtin_amdgcn_update_dpp(0, __float_as_int(x), 0x4E, 0xF, 0xF, true));  // quad_perm xor2
  x += __int_as_float(__builtin_amdgcn_update_dpp(0, __float_as_int(x), 0x141, 0xF, 0xF, true)); // row_half_mirror
  x += __int_as_float(__builtin_amdgcn_update_dpp(0, __float_as_int(x), 0x140, 0xF, 0xF, true)); // row_mirror
  return x;
}

__device__ __forceinline__ void unpk8(const uint4 p, float* f) {
  f[0] = __uint_as_float(p.x << 16); f[1] = __uint_as_float(p.x & 0xFFFF0000u);
  f[2] = __uint_as_float(p.y << 16); f[3] = __uint_as_float(p.y & 0xFFFF0000u);
  f[4] = __uint_as_float(p.z << 16); f[5] = __uint_as_float(p.z & 0xFFFF0000u);
  f[6] = __uint_as_float(p.w << 16); f[7] = __uint_as_float(p.w & 0xFFFF0000u);
}

// C[M,N] = act(A[M,K] @ W[N,K]^T). bf16 in, fp32 or bf16 out.
__global__ __launch_bounds__(256) void gemm_bf16_nt(
    const ushort_t* __restrict__ A, const ushort_t* __restrict__ W,
    float* __restrict__ Cf, ushort_t* __restrict__ Cb,
    int M, int N, int K, int act, const float* __restrict__ bias,
    const float* __restrict__ A_log, const float* __restrict__ dt_bias) {
  __shared__ alignas(16) ushort_t As[4096];
  __shared__ alignas(16) ushort_t Bs[4096];
  const int tid = threadIdx.x;
  const int wv = tid >> 6, ln = tid & 63;
  const int bm = blockIdx.y * 128, bn = blockIdx.x * 128;
  const int wm = wv >> 1, wn = wv & 1;

  const int srow = tid >> 2;
  const int skg = (tid & 3) ^ ((srow >> 1) & 3);
  const size_t ag0 = (size_t)(bm + srow) * K + skg * 8;
  const size_t ag1 = ag0 + (size_t)64 * K;
  const size_t bg0 = (size_t)(bn + srow) * K + skg * 8;
  const size_t bg1 = bg0 + (size_t)64 * K;
  char* const lA = (char*)As;
  char* const lB = (char*)Bs;
  const int wbase = wv * 1024;

  const int fr = ln & 15, fq = ln >> 4;
  const int pg = fq ^ ((fr >> 1) & 3);
  int aoff[4], boff[4];
#pragma unroll
  for (int i = 0; i < 4; i++) {
    aoff[i] = (wm * 64 + i * 16 + fr) * 64 + pg * 16;
    boff[i] = (wn * 64 + i * 16 + fr) * 64 + pg * 16;
  }

  f32x4 acc[4][4];
#pragma unroll
  for (int i = 0; i < 4; i++)
#pragma unroll
    for (int j = 0; j < 4; j++) {
      acc[i][j][0] = 0.f; acc[i][j][1] = 0.f; acc[i][j][2] = 0.f; acc[i][j][3] = 0.f;
    }

  for (int k0 = 0; k0 < K; k0 += 32) {
    gld_lds16(A + ag0 + k0, lA + wbase);
    gld_lds16(A + ag1 + k0, lA + 4096 + wbase);
    gld_lds16(W + bg0 + k0, lB + wbase);
    gld_lds16(W + bg1 + k0, lB + 4096 + wbase);
    __syncthreads();
    short8 af[4], bf[4];
#pragma unroll
    for (int i = 0; i < 4; i++) af[i] = *(const short8*)(lA + aoff[i]);
#pragma unroll
    for (int i = 0; i < 4; i++) bf[i] = *(const short8*)(lB + boff[i]);
#pragma unroll
    for (int i = 0; i < 4; i++)
#pragma unroll
      for (int j = 0; j < 4; j++)
        acc[i][j] = __builtin_amdgcn_mfma_f32_16x16x32_bf16(af[i], bf[j], acc[i][j], 0, 0, 0);
    __syncthreads();
  }

  const int cc = ln & 15, cq = ln >> 4;
#pragma unroll
  for (int i = 0; i < 4; i++) {
#pragma unroll
    for (int r = 0; r < 4; r++) {
      const int gm = bm + wm * 64 + i * 16 + cq * 4 + r;
#pragma unroll
      for (int j = 0; j < 4; j++) {
        const int gn = bn + wn * 64 + j * 16 + cc;
        float x = epi_act(acc[i][j][r], act, gn, bias, A_log, dt_bias);
        if (Cb) Cb[(size_t)gm * N + gn] = f32_to_bf16(x);
        else    Cf[(size_t)gm * N + gn] = x;
      }
    }
  }
}

// fp32 GEMM (beta projection, N=16)
#define BM 128
#define BN 128
#define BKK 8
__global__ __launch_bounds__(256) void gemm_nt(
    const float* __restrict__ A, const float* __restrict__ W,
    float* __restrict__ C, int M, int N, int K, int act) {
  __shared__ alignas(16) float Asf[BKK][BM + 4];
  __shared__ alignas(16) float Wsf[BKK][BN + 4];
  const int tid = threadIdx.x;
  const int bm = blockIdx.y * BM;
  const int bn = blockIdx.x * BN;
  const int tn = tid & 15, tm = tid >> 4;
  const int lrow = tid >> 1;
  const int lk = (tid & 1) * 4;

  float acc[8][8];
#pragma unroll
  for (int i = 0; i < 8; i++)
#pragma unroll
    for (int j = 0; j < 8; j++) acc[i][j] = 0.f;

  for (int k0 = 0; k0 < K; k0 += BKK) {
    const float4 a4 = *(const float4*)&A[(size_t)(bm + lrow) * K + k0 + lk];
    float4 w4 = make_float4(0.f, 0.f, 0.f, 0.f);
    if (bn + lrow < N) w4 = *(const float4*)&W[(size_t)(bn + lrow) * K + k0 + lk];
    __syncthreads();
    Asf[lk + 0][lrow] = a4.x; Asf[lk + 1][lrow] = a4.y;
    Asf[lk + 2][lrow] = a4.z; Asf[lk + 3][lrow] = a4.w;
    Wsf[lk + 0][lrow] = w4.x; Wsf[lk + 1][lrow] = w4.y;
    Wsf[lk + 2][lrow] = w4.z; Wsf[lk + 3][lrow] = w4.w;
    __syncthreads();
#pragma unroll
    for (int kk = 0; kk < BKK; kk++) {
      const float4 a0 = *(const float4*)&Asf[kk][tm * 8];
      const float4 a1 = *(const float4*)&Asf[kk][tm * 8 + 4];
      const float4 b0 = *(const float4*)&Wsf[kk][tn * 8];
      const float4 b1 = *(const float4*)&Wsf[kk][tn * 8 + 4];
      const float av[8] = {a0.x, a0.y, a0.z, a0.w, a1.x, a1.y, a1.z, a1.w};
      const float bv[8] = {b0.x, b0.y, b0.z, b0.w, b1.x, b1.y, b1.z, b1.w};
#pragma unroll
      for (int i = 0; i < 8; i++)
#pragma unroll
        for (int j = 0; j < 8; j++) acc[i][j] = fmaf(av[i], bv[j], acc[i][j]);
    }
  }
#pragma unroll
  for (int i = 0; i < 8; i++) {
    const int m = bm + tm * 8 + i;
#pragma unroll
    for (int j = 0; j < 8; j++) {
      const int n = bn + tn * 8 + j;
      if (n < N) {
        float x = acc[i][j];
        if (act == ACT_SIGMOID) x = 1.f / (1.f + __expf(-x));
        C[(size_t)m * N + n] = x;
      }
    }
  }
}

__global__ __launch_bounds__(256) void cast_bf16(const float* __restrict__ x,
                                                 ushort_t* __restrict__ y, int n) {
  const int i = (blockIdx.x * 256 + threadIdx.x) * 4;
  if (i >= n) return;
  const float4 v = *(const float4*)&x[i];
  union { ushort_t u[4]; uint2 v2; } o;
  o.u[0] = f32_to_bf16(v.x); o.u[1] = f32_to_bf16(v.y);
  o.u[2] = f32_to_bf16(v.z); o.u[3] = f32_to_bf16(v.w);
  *(uint2*)&y[i] = o.v2;
}

// fp32 in -> l2norm (scale folded) -> bf16 out, rows of 128
__global__ __launch_bounds__(64) void l2norm_bf16(const float* __restrict__ x,
                                                  ushort_t* __restrict__ y, float scale) {
  const size_t base = (size_t)blockIdx.x * 128;
  const int lane = threadIdx.x;
  const float a = x[base + lane];
  const float b = x[base + lane + 64];
  float ss = fmaf(a, a, b * b);
#pragma unroll
  for (int m = 1; m < 64; m <<= 1) ss += __shfl_xor(ss, m);
  const float r = rsqrtf(ss + 1e-6f) * scale;
  y[base + lane] = f32_to_bf16(a * r);
  y[base + lane + 64] = f32_to_bf16(b * r);
}

// ---------------------------------------------------------------------------
// Barrier-free gated delta-rule scan, v3.
// grid = 2048 (64 bh x 32 colgroups, XCD-swizzled), block = 64 (one wave).
// Lane: cl = ln>>4 (4 cols), kg = ln&15 (16-way k-split), S[8]/lane.
// q,k bf16; ge fp32 (exp of gate); o -> SEPARATE buffer (no aliasing).
// 4-slot rotating register prefetch; DPP reductions.
// ---------------------------------------------------------------------------
struct StepRegs { uint4 kp, qp; float4 g0, g1; float vv, bb; };

__global__ __launch_bounds__(64) void kda_scan(
    const ushort_t* __restrict__ q, const ushort_t* __restrict__ k,
    const float* __restrict__ v, const float* __restrict__ ge,
    const float* __restrict__ beta, const float* __restrict__ S0,
    float* __restrict__ o, float* __restrict__ S_out) {
  const int bid = blockIdx.x;
  const int bh = (((bid >> 3) & 7) << 3) | (bid & 7);  // same-bh -> same XCD
  const int cg = bid >> 6;
  const int h = bh & 15, b = bh >> 4;
  const int ln = threadIdx.x;
  const int cl = ln >> 4, kg = ln & 15;
  const int col = cg * 4 + cl;
  const int kof = kg * 8;

  const size_t s_base = (size_t)bh * (128 * 128);
  float S[8];
#pragma unroll
  for (int j = 0; j < 8; j++) S[j] = S0[s_base + (size_t)(kof + j) * 128 + col];

  const size_t rb = (size_t)b * (2048 * 2048) + (size_t)h * 128;
  const size_t bbase = (size_t)(b * 2048) * 16 + h;

  StepRegs sr[4];
#pragma unroll
  for (int s = 0; s < 4; s++) {
    const size_t a = rb + (size_t)s * 2048;
    sr[s].kp = *(const uint4*)&k[a + kof];
    sr[s].qp = *(const uint4*)&q[a + kof];
    sr[s].g0 = *(const float4*)&ge[a + kof];
    sr[s].g1 = *(const float4*)&ge[a + kof + 4];
    sr[s].vv = v[a + col];
    sr[s].bb = beta[bbase + (size_t)s * 16];
  }

  for (int t = 0; t < 2048; t += 4) {
#pragma unroll
    for (int s = 0; s < 4; s++) {
      const int tt = t + s;
      // --- compute step tt from slot s ---
      float kf[8], qf[8];
      unpk8(sr[s].kp, kf);
      unpk8(sr[s].qp, qf);
      const float4 g0 = sr[s].g0, g1 = sr[s].g1;
      float p0 = 0.f, p1 = 0.f;
      S[0] *= g0.x; p0 = fmaf(kf[0], S[0], p0);
      S[1] *= g0.y; p1 = fmaf(kf[1], S[1], p1);
      S[2] *= g0.z; p0 = fmaf(kf[2], S[2], p0);
      S[3] *= g0.w; p1 = fmaf(kf[3], S[3], p1);
      S[4] *= g1.x; p0 = fmaf(kf[4], S[4], p0);
      S[5] *= g1.y; p1 = fmaf(kf[5], S[5], p1);
      S[6] *= g1.z; p0 = fmaf(kf[6], S[6], p0);
      S[7] *= g1.w; p1 = fmaf(kf[7], S[7], p1);
      const float p = row16_sum(p0 + p1);
      const float delta = (sr[s].vv - p) * sr[s].bb;
      float o0 = 0.f, o1 = 0.f;
      S[0] = fmaf(kf[0], delta, S[0]); o0 = fmaf(qf[0], S[0], o0);
      S[1] = fmaf(kf[1], delta, S[1]); o1 = fmaf(qf[1], S[1], o1);
      S[2] = fmaf(kf[2], delta, S[2]); o0 = fmaf(qf[2], S[2], o0);
      S[3] = fmaf(kf[3], delta, S[3]); o1 = fmaf(qf[3], S[3], o1);
      S[4] = fmaf(kf[4], delta, S[4]); o0 = fmaf(qf[4], S[4], o0);
      S[5] = fmaf(kf[5], delta, S[5]); o1 = fmaf(qf[5], S[5], o1);
      S[6] = fmaf(kf[6], delta, S[6]); o0 = fmaf(qf[6], S[6], o0);
      S[7] = fmaf(kf[7], delta, S[7]); o1 = fmaf(qf[7], S[7], o1);
      const float op = row16_sum(o0 + o1);
      if (kg == 0) o[rb + (size_t)tt * 2048 + col] = op;
      // --- refill slot s with step tt+4 (depth-3..4 prefetch) ---
      const int tn = (tt + 4 < 2048) ? tt + 4 : 2047;
      const size_t a = rb + (size_t)tn * 2048;
      sr[s].kp = *(const uint4*)&k[a + kof];
      sr[s].qp = *(const uint4*)&q[a + kof];
      sr[s].g0 = *(const float4*)&ge[a + kof];
      sr[s].g1 = *(const float4*)&ge[a + kof + 4];
      sr[s].vv = v[a + col];
      sr[s].bb = beta[bbase + (size_t)tn * 16];
    }
  }
#pragma unroll
  for (int j = 0; j < 8; j++)
    S_out[s_base + (size_t)(kof + j) * 128 + col] = S[j];
}

// out_bf16 = rms(o)*w*sigmoid(factor)
__global__ __launch_bounds__(128) void gate_rmsnorm(
    const float* __restrict__ o, const float* __restrict__ factor,
    const float* __restrict__ w, ushort_t* __restrict__ out) {
  const size_t base = (size_t)blockIdx.x * 128;
  const int vi = threadIdx.x;
  const float x = o[base + vi];
  float ss = x * x;
#pragma unroll
  for (int m = 1; m < 64; m <<= 1) ss += __shfl_xor(ss, m);
  __shared__ float red[2];
  if ((vi & 63) == 0) red[vi >> 6] = ss;
  __syncthreads();
  const float tot = red[0] + red[1];
  const float r = rsqrtf(tot * (1.f / 128.f) + 1e-5f);
  const float f = factor[base + vi];
  const float sig = 1.f / (1.f + __expf(-f));
  out[base + vi] = f32_to_bf16(x * r * w[vi] * sig);
}

extern "C" void kernel_launch(void* const* d_in, const int* in_sizes, int n_in,
                              void* d_out, int out_size, void* d_ws, size_t ws_size,
                              hipStream_t stream) {
  const float* h    = (const float*)d_in[0];
  const float* S0   = (const float*)d_in[1];
  const float* q_w  = (const float*)d_in[2];
  const float* k_w  = (const float*)d_in[3];
  const float* v_w  = (const float*)d_in[4];
  const float* f_w0 = (const float*)d_in[5];
  const float* f_w1 = (const float*)d_in[6];
  const float* b_w  = (const float*)d_in[7];
  const float* A_log  = (const float*)d_in[8];
  const float* dt_b   = (const float*)d_in[9];
  const float* g_w0 = (const float*)d_in[10];
  const float* g_w1 = (const float*)d_in[11];
  const float* g_b1 = (const float*)d_in[12];
  const float* o_nw = (const float*)d_in[13];
  const float* o_w  = (const float*)d_in[14];

  float* outp = (float*)d_out;                 // exp(g) -> factor -> final out
  float* Sout = outp + (size_t)8192 * 2048;

  const size_t BIG = (size_t)8192 * 2048;
  float* ws = (float*)d_ws;
  float* vbuf = ws;                                   // f32 v
  float* obuf = vbuf + BIG;                           // f32: q/k pre-norm temp, then scan o
  float* betab = obuf + BIG;                          // 8192*16 f32
  ushort_t* qb16 = (ushort_t*)(betab + (size_t)8192 * 16);  // bf16 q; later gated-o bf16
  ushort_t* kb16 = qb16 + BIG;
  ushort_t* hb   = kb16 + BIG;
  ushort_t* wq   = hb + BIG;
  ushort_t* wk   = wq + (size_t)2048 * 2048;
  ushort_t* wv   = wk + (size_t)2048 * 2048;
  ushort_t* wo   = wv + (size_t)2048 * 2048;
  ushort_t* wf0  = wo + (size_t)2048 * 2048;
  ushort_t* wg0  = wf0 + (size_t)128 * 2048;
  ushort_t* wf1  = wg0 + (size_t)128 * 2048;
  ushort_t* wg1  = wf1 + (size_t)2048 * 128;
  ushort_t* fpreb = wg1 + (size_t)2048 * 128;
  ushort_t* gpreb = fpreb + (size_t)8192 * 128;

  const dim3 blk(256);
  const dim3 gbig(16, 64);
  const dim3 gnarrow(1, 64);

  // casts
  cast_bf16<<<16384, blk, 0, stream>>>(h, hb, 8192 * 2048);
  cast_bf16<<<4096, blk, 0, stream>>>(q_w, wq, 2048 * 2048);
  cast_bf16<<<4096, blk, 0, stream>>>(k_w, wk, 2048 * 2048);
  cast_bf16<<<4096, blk, 0, stream>>>(v_w, wv, 2048 * 2048);
  cast_bf16<<<4096, blk, 0, stream>>>(o_w, wo, 2048 * 2048);
  cast_bf16<<<256, blk, 0, stream>>>(f_w0, wf0, 128 * 2048);
  cast_bf16<<<256, blk, 0, stream>>>(g_w0, wg0, 128 * 2048);
  cast_bf16<<<256, blk, 0, stream>>>(f_w1, wf1, 2048 * 128);
  cast_bf16<<<256, blk, 0, stream>>>(g_w1, wg1, 2048 * 128);

  // q: GEMM -> obuf (f32), l2norm -> qb16 (scale folded)
  gemm_bf16_nt<<<gbig, blk, 0, stream>>>(hb, wq, obuf, nullptr, 8192, 2048, 2048, ACT_SILU, nullptr, nullptr, nullptr);
  l2norm_bf16<<<131072, 64, 0, stream>>>(obuf, qb16, 0.08838834764831845f);
  // k
  gemm_bf16_nt<<<gbig, blk, 0, stream>>>(hb, wk, obuf, nullptr, 8192, 2048, 2048, ACT_SILU, nullptr, nullptr, nullptr);
  l2norm_bf16<<<131072, 64, 0, stream>>>(obuf, kb16, 1.0f);
  // v
  gemm_bf16_nt<<<gbig, blk, 0, stream>>>(hb, wv, vbuf, nullptr, 8192, 2048, 2048, ACT_SILU, nullptr, nullptr, nullptr);
  // low-rank pre-projections + beta
  gemm_bf16_nt<<<gnarrow, blk, 0, stream>>>(hb, wf0, nullptr, fpreb, 8192, 128, 2048, ACT_NONE, nullptr, nullptr, nullptr);
  gemm_bf16_nt<<<gnarrow, blk, 0, stream>>>(hb, wg0, nullptr, gpreb, 8192, 128, 2048, ACT_NONE, nullptr, nullptr, nullptr);
  gemm_nt<<<gnarrow, blk, 0, stream>>>(h, b_w, betab, 8192, 16, 2048, ACT_SIGMOID);
  // exp(g) -> outp
  gemm_bf16_nt<<<gbig, blk, 0, stream>>>(fpreb, wf1, outp, nullptr, 8192, 2048, 128, ACT_KDAGATE_EXP, nullptr, A_log, dt_b);
  // scan: o -> obuf (q/k temps dead), S -> d_out tail
  kda_scan<<<2048, 64, 0, stream>>>(qb16, kb16, vbuf, outp, betab, S0, obuf, Sout);
  // factor = gpre @ g_w1.T + g_b1 -> outp (exp(g) dead)
  gemm_bf16_nt<<<gbig, blk, 0, stream>>>(gpreb, wg1, outp, nullptr, 8192, 2048, 128, ACT_NONE, g_b1, nullptr, nullptr);
  // gated rmsnorm -> bf16 into qb16 (dead after scan)
  gate_rmsnorm<<<131072, 128, 0, stream>>>(obuf, outp, o_nw, qb16);
  // out = gated_o @ o_w.T -> outp
  gemm_bf16_nt<<<gbig, blk, 0, stream>>>(qb16, wo, outp, nullptr, 8192, 2048, 2048, ACT_NONE, nullptr, nullptr, nullptr);
}

// Round 4
// 2092.796 us; speedup vs baseline: 3.2397x; 1.0180x over previous
//
#include <hip/hip_runtime.h>
#include <math.h>

// ---------------------------------------------------------------------------
// KimiDeltaAttention B=4 T=2048 HID=2048 H=16 DK=DV=128
//  - one fused QKV bf16 MFMA GEMM (N=6144) with silu+l2norm in epilogue
//  - one fused lowrank GEMM (fpre|gpre|beta, N=384 padded)
//  - scan v4: fp32 q/k (no unpack), 3 parallel DPP reductions
//    (k.S, q.S, q.k), o = q.S_dec + (q.k)*delta, 4-slot prefetch
// ---------------------------------------------------------------------------

typedef short short8 __attribute__((ext_vector_type(8)));
typedef float f32x4 __attribute__((ext_vector_type(4)));
typedef unsigned short ushort_t;

// gemm epilogue modes
enum { M_PLAIN = 0, M_QKV = 1, M_LOWRANK = 2, M_GATE = 3, M_FACTOR = 4 };

__device__ __forceinline__ unsigned short f32_to_bf16(float f) {
  unsigned int u = __float_as_uint(f);
  u += 0x7FFFu + ((u >> 16) & 1u);   // RNE
  return (unsigned short)(u >> 16);
}

__device__ __forceinline__ float silu(float x) { return x / (1.f + __expf(-x)); }

__device__ __forceinline__ void gld_lds16(const void* g, void* l) {
  __builtin_amdgcn_global_load_lds(
      (const __attribute__((address_space(1))) unsigned int*)g,
      (__attribute__((address_space(3))) unsigned int*)l, 16, 0, 0);
}

// sum across each aligned 16-lane group, pure DPP
__device__ __forceinline__ float row16_sum(float x) {
  x += __int_as_float(__builtin_amdgcn_update_dpp(0, __float_as_int(x), 0xB1, 0xF, 0xF, true));
  x += __int_as_float(__builtin_amdgcn_update_dpp(0, __float_as_int(x), 0x4E, 0xF, 0xF, true));
  x += __int_as_float(__builtin_amdgcn_update_dpp(0, __float_as_int(x), 0x141, 0xF, 0xF, true));
  x += __int_as_float(__builtin_amdgcn_update_dpp(0, __float_as_int(x), 0x140, 0xF, 0xF, true));
  return x;
}

// ---------------------------------------------------------------------------
// bf16 MFMA GEMM, 128x128 tile, m97 structure + mode-switched epilogue.
// ---------------------------------------------------------------------------
__global__ __launch_bounds__(256) void gemm_bf16(
    const ushort_t* __restrict__ A, const ushort_t* __restrict__ W,
    int M, int N, int K, int mode,
    float* __restrict__ f0, float* __restrict__ f1, float* __restrict__ f2,
    ushort_t* __restrict__ b0, ushort_t* __restrict__ b1,
    const float* __restrict__ bias, const float* __restrict__ A_log,
    const float* __restrict__ dt_bias) {
  __shared__ alignas(16) ushort_t As[4096];
  __shared__ alignas(16) ushort_t Bs[4096];
  __shared__ float l2s[2][128];
  const int tid = threadIdx.x;
  const int wv = tid >> 6, ln = tid & 63;
  const int bm = blockIdx.y * 128, bn = blockIdx.x * 128;
  const int wm = wv >> 1, wn = wv & 1;

  const int srow = tid >> 2;
  const int skg = (tid & 3) ^ ((srow >> 1) & 3);
  const size_t ag0 = (size_t)(bm + srow) * K + skg * 8;
  const size_t ag1 = ag0 + (size_t)64 * K;
  const size_t bg0 = (size_t)(bn + srow) * K + skg * 8;
  const size_t bg1 = bg0 + (size_t)64 * K;
  char* const lA = (char*)As;
  char* const lB = (char*)Bs;
  const int wbase = wv * 1024;

  const int fr = ln & 15, fq = ln >> 4;
  const int pg = fq ^ ((fr >> 1) & 3);
  int aoff[4], boff[4];
#pragma unroll
  for (int i = 0; i < 4; i++) {
    aoff[i] = (wm * 64 + i * 16 + fr) * 64 + pg * 16;
    boff[i] = (wn * 64 + i * 16 + fr) * 64 + pg * 16;
  }

  f32x4 acc[4][4];
#pragma unroll
  for (int i = 0; i < 4; i++)
#pragma unroll
    for (int j = 0; j < 4; j++) {
      acc[i][j][0] = 0.f; acc[i][j][1] = 0.f; acc[i][j][2] = 0.f; acc[i][j][3] = 0.f;
    }

  for (int k0 = 0; k0 < K; k0 += 32) {
    gld_lds16(A + ag0 + k0, lA + wbase);
    gld_lds16(A + ag1 + k0, lA + 4096 + wbase);
    gld_lds16(W + bg0 + k0, lB + wbase);
    gld_lds16(W + bg1 + k0, lB + 4096 + wbase);
    __syncthreads();
    short8 af[4], bf[4];
#pragma unroll
    for (int i = 0; i < 4; i++) af[i] = *(const short8*)(lA + aoff[i]);
#pragma unroll
    for (int i = 0; i < 4; i++) bf[i] = *(const short8*)(lB + boff[i]);
#pragma unroll
    for (int i = 0; i < 4; i++)
#pragma unroll
      for (int j = 0; j < 4; j++)
        acc[i][j] = __builtin_amdgcn_mfma_f32_16x16x32_bf16(af[i], bf[j], acc[i][j], 0, 0, 0);
    __syncthreads();
  }

  // C/D layout: col = ln&15, row = (ln>>4)*4 + reg
  const int cc = ln & 15, cq = ln >> 4;

  if (mode == M_QKV) {
    // silu in place
#pragma unroll
    for (int i = 0; i < 4; i++)
#pragma unroll
      for (int j = 0; j < 4; j++)
#pragma unroll
        for (int r = 0; r < 4; r++) acc[i][j][r] = silu(acc[i][j][r]);
    const bool isqk = (bn < 4096);
    float invr[4][4];
    if (isqk) {
      const float scale = (bn < 2048) ? 0.08838834764831845f : 1.0f;
#pragma unroll
      for (int i = 0; i < 4; i++)
#pragma unroll
        for (int r = 0; r < 4; r++) {
          float ss = 0.f;
#pragma unroll
          for (int j = 0; j < 4; j++) ss = fmaf(acc[i][j][r], acc[i][j][r], ss);
          ss = row16_sum(ss);
          if (cc == 0) l2s[wn][wm * 64 + i * 16 + cq * 4 + r] = ss;
        }
      __syncthreads();
#pragma unroll
      for (int i = 0; i < 4; i++)
#pragma unroll
        for (int r = 0; r < 4; r++) {
          const int rl = wm * 64 + i * 16 + cq * 4 + r;
          invr[i][r] = rsqrtf(l2s[0][rl] + l2s[1][rl] + 1e-6f) * scale;
        }
    } else {
#pragma unroll
      for (int i = 0; i < 4; i++)
#pragma unroll
        for (int r = 0; r < 4; r++) invr[i][r] = 1.f;
    }
    float* dst = (bn < 2048) ? f0 : ((bn < 4096) ? f1 : f2);
    const int nb = bn & 2047;
#pragma unroll
    for (int i = 0; i < 4; i++)
#pragma unroll
      for (int r = 0; r < 4; r++) {
        const int gm = bm + wm * 64 + i * 16 + cq * 4 + r;
#pragma unroll
        for (int j = 0; j < 4; j++) {
          const int gn = nb + wn * 64 + j * 16 + cc;
          dst[(size_t)gm * 2048 + gn] = acc[i][j][r] * invr[i][r];
        }
      }
    return;
  }

  if (mode == M_LOWRANK) {
#pragma unroll
    for (int i = 0; i < 4; i++)
#pragma unroll
      for (int r = 0; r < 4; r++) {
        const int gm = bm + wm * 64 + i * 16 + cq * 4 + r;
#pragma unroll
        for (int j = 0; j < 4; j++) {
          const int gn = bn + wn * 64 + j * 16 + cc;
          const float x = acc[i][j][r];
          if (gn < 128) b0[(size_t)gm * 128 + gn] = f32_to_bf16(x);
          else if (gn < 256) b1[(size_t)gm * 128 + (gn - 128)] = f32_to_bf16(x);
          else if (gn < 272) f0[(size_t)gm * 16 + (gn - 256)] = 1.f / (1.f + __expf(-x));
        }
      }
    return;
  }

  // M_PLAIN / M_GATE / M_FACTOR -> f32, stride N
#pragma unroll
  for (int i = 0; i < 4; i++)
#pragma unroll
    for (int r = 0; r < 4; r++) {
      const int gm = bm + wm * 64 + i * 16 + cq * 4 + r;
#pragma unroll
      for (int j = 0; j < 4; j++) {
        const int gn = bn + wn * 64 + j * 16 + cc;
        float x = acc[i][j][r];
        if (mode == M_FACTOR) x += bias[gn];
        else if (mode == M_GATE) {
          const float y = x + dt_bias[gn];
          const float sp = fmaxf(y, 0.f) + log1pf(__expf(-fabsf(y)));
          x = __expf(-__expf(A_log[gn >> 7]) * sp);
        }
        f0[(size_t)gm * N + gn] = x;
      }
    }
}

__global__ __launch_bounds__(256) void cast_bf16(const float* __restrict__ x,
                                                 ushort_t* __restrict__ y, int n) {
  const int i = (blockIdx.x * 256 + threadIdx.x) * 4;
  if (i >= n) return;
  const float4 v = *(const float4*)&x[i];
  union { ushort_t u[4]; uint2 v2; } o;
  o.u[0] = f32_to_bf16(v.x); o.u[1] = f32_to_bf16(v.y);
  o.u[2] = f32_to_bf16(v.z); o.u[3] = f32_to_bf16(v.w);
  *(uint2*)&y[i] = o.v2;
}

// ---------------------------------------------------------------------------
// Barrier-free gated delta-rule scan, v4. fp32 q/k/ge.
// grid = 2048 (64 bh x 32 colgroups, XCD-swizzled), block = 64 (one wave).
// Lane: cl = ln>>4 (4 cols), kg = ln&15 (16-way k-split), S[8]/lane.
// Single-phase: k.S, q.S_dec, q.k reduced in parallel (DPP);
// o = q.S_dec + (q.k)*delta. 4-slot rotating prefetch.
// ---------------------------------------------------------------------------
__global__ __launch_bounds__(64) void kda_scan(
    const float* __restrict__ q, const float* __restrict__ k,
    const float* __restrict__ v, const float* __restrict__ ge,
    const float* __restrict__ beta, const float* __restrict__ S0,
    float* __restrict__ o, float* __restrict__ S_out) {
  const int bid = blockIdx.x;
  const int bh = (((bid >> 3) & 7) << 3) | (bid & 7);
  const int cg = bid >> 6;
  const int h = bh & 15, b = bh >> 4;
  const int ln = threadIdx.x;
  const int cl = ln >> 4, kg = ln & 15;
  const int col = cg * 4 + cl;
  const int kof = kg * 8;

  const size_t s_base = (size_t)bh * (128 * 128);
  float S[8];
#pragma unroll
  for (int j = 0; j < 8; j++) S[j] = S0[s_base + (size_t)(kof + j) * 128 + col];

  const size_t rb = (size_t)b * (2048 * 2048) + (size_t)h * 128;
  const size_t bbase = (size_t)(b * 2048) * 16 + h;

  float4 sk0[4], sk1[4], sq0[4], sq1[4], sg0[4], sg1[4];
  float sv[4], sb[4];
#pragma unroll
  for (int s = 0; s < 4; s++) {
    const size_t a = rb + (size_t)s * 2048;
    sk0[s] = *(const float4*)&k[a + kof];  sk1[s] = *(const float4*)&k[a + kof + 4];
    sq0[s] = *(const float4*)&q[a + kof];  sq1[s] = *(const float4*)&q[a + kof + 4];
    sg0[s] = *(const float4*)&ge[a + kof]; sg1[s] = *(const float4*)&ge[a + kof + 4];
    sv[s] = v[a + col];
    sb[s] = beta[bbase + (size_t)s * 16];
  }

  for (int t = 0; t < 2048; t += 4) {
#pragma unroll
    for (int s = 0; s < 4; s++) {
      const float4 K0 = sk0[s], K1 = sk1[s], Q0 = sq0[s], Q1 = sq1[s];
      const float4 G0 = sg0[s], G1 = sg1[s];
      const float VV = sv[s], BB = sb[s];
      // refill slot s for step t+s+4 (loads overlap compute below)
      {
        int tn = t + s + 4; if (tn > 2047) tn = 2047;
        const size_t a = rb + (size_t)tn * 2048;
        sk0[s] = *(const float4*)&k[a + kof];  sk1[s] = *(const float4*)&k[a + kof + 4];
        sq0[s] = *(const float4*)&q[a + kof];  sq1[s] = *(const float4*)&q[a + kof + 4];
        sg0[s] = *(const float4*)&ge[a + kof]; sg1[s] = *(const float4*)&ge[a + kof + 4];
        sv[s] = v[a + col];
        sb[s] = beta[bbase + (size_t)tn * 16];
      }
      float p0 = 0.f, p1 = 0.f, o0 = 0.f, o1 = 0.f, d0 = 0.f, d1 = 0.f;
      S[0] *= G0.x; p0 = fmaf(K0.x, S[0], p0); o0 = fmaf(Q0.x, S[0], o0); d0 = fmaf(Q0.x, K0.x, d0);
      S[1] *= G0.y; p1 = fmaf(K0.y, S[1], p1); o1 = fmaf(Q0.y, S[1], o1); d1 = fmaf(Q0.y, K0.y, d1);
      S[2] *= G0.z; p0 = fmaf(K0.z, S[2], p0); o0 = fmaf(Q0.z, S[2], o0); d0 = fmaf(Q0.z, K0.z, d0);
      S[3] *= G0.w; p1 = fmaf(K0.w, S[3], p1); o1 = fmaf(Q0.w, S[3], o1); d1 = fmaf(Q0.w, K0.w, d1);
      S[4] *= G1.x; p0 = fmaf(K1.x, S[4], p0); o0 = fmaf(Q1.x, S[4], o0); d0 = fmaf(Q1.x, K1.x, d0);
      S[5] *= G1.y; p1 = fmaf(K1.y, S[5], p1); o1 = fmaf(Q1.y, S[5], o1); d1 = fmaf(Q1.y, K1.y, d1);
      S[6] *= G1.z; p0 = fmaf(K1.z, S[6], p0); o0 = fmaf(Q1.z, S[6], o0); d0 = fmaf(Q1.z, K1.z, d0);
      S[7] *= G1.w; p1 = fmaf(K1.w, S[7], p1); o1 = fmaf(Q1.w, S[7], o1); d1 = fmaf(Q1.w, K1.w, d1);
      const float p  = row16_sum(p0 + p1);
      const float oq = row16_sum(o0 + o1);
      const float qk = row16_sum(d0 + d1);
      const float delta = (VV - p) * BB;
      const float op = fmaf(qk, delta, oq);
      if (kg == 0) o[rb + (size_t)(t + s) * 2048 + col] = op;
      S[0] = fmaf(K0.x, delta, S[0]);
      S[1] = fmaf(K0.y, delta, S[1]);
      S[2] = fmaf(K0.z, delta, S[2]);
      S[3] = fmaf(K0.w, delta, S[3]);
      S[4] = fmaf(K1.x, delta, S[4]);
      S[5] = fmaf(K1.y, delta, S[5]);
      S[6] = fmaf(K1.z, delta, S[6]);
      S[7] = fmaf(K1.w, delta, S[7]);
    }
  }
#pragma unroll
  for (int j = 0; j < 8; j++)
    S_out[s_base + (size_t)(kof + j) * 128 + col] = S[j];
}

// out_bf16 = rms(o)*w*sigmoid(factor). grid 2048 x 256: 64 rows/block.
__global__ __launch_bounds__(256) void gate_rmsnorm(
    const float* __restrict__ o, const float* __restrict__ factor,
    const float* __restrict__ w, ushort_t* __restrict__ out) {
  const int ln = threadIdx.x & 63, wv = threadIdx.x >> 6;
  const float w0 = w[ln * 2], w1 = w[ln * 2 + 1];
  const size_t row0 = (size_t)blockIdx.x * 64 + wv * 16;
  for (int it = 0; it < 16; it++) {
    const size_t base = (row0 + it) * 128 + ln * 2;
    const float2 x = *(const float2*)&o[base];
    const float2 f = *(const float2*)&factor[base];
    float ss = fmaf(x.x, x.x, x.y * x.y);
    ss = row16_sum(ss);
    ss += __shfl_xor(ss, 16);
    ss += __shfl_xor(ss, 32);
    const float r = rsqrtf(ss * (1.f / 128.f) + 1e-5f);
    const float y0 = x.x * r * w0 / (1.f + __expf(-f.x));
    const float y1 = x.y * r * w1 / (1.f + __expf(-f.y));
    *(unsigned int*)&out[base] =
        (unsigned int)f32_to_bf16(y0) | ((unsigned int)f32_to_bf16(y1) << 16);
  }
}

extern "C" void kernel_launch(void* const* d_in, const int* in_sizes, int n_in,
                              void* d_out, int out_size, void* d_ws, size_t ws_size,
                              hipStream_t stream) {
  const float* h    = (const float*)d_in[0];
  const float* S0   = (const float*)d_in[1];
  const float* q_w  = (const float*)d_in[2];
  const float* k_w  = (const float*)d_in[3];
  const float* v_w  = (const float*)d_in[4];
  const float* f_w0 = (const float*)d_in[5];
  const float* f_w1 = (const float*)d_in[6];
  const float* b_w  = (const float*)d_in[7];
  const float* A_log  = (const float*)d_in[8];
  const float* dt_b   = (const float*)d_in[9];
  const float* g_w0 = (const float*)d_in[10];
  const float* g_w1 = (const float*)d_in[11];
  const float* g_b1 = (const float*)d_in[12];
  const float* o_nw = (const float*)d_in[13];
  const float* o_w  = (const float*)d_in[14];

  float* outp = (float*)d_out;                 // exp(g) -> factor -> final out
  float* Sout = outp + (size_t)8192 * 2048;

  const size_t BIG = (size_t)8192 * 2048;   // 16.8M elems
  float* ws = (float*)d_ws;
  float* vbuf  = ws;                         // f32 [BIG]
  float* qbuf  = vbuf + BIG;                 // f32 [BIG]; gated bf16 reuses this
  float* kbuf  = qbuf + BIG;                 // f32 [BIG]
  float* betab = kbuf + BIG;                 // f32 [8192*16]
  ushort_t* fpreb = (ushort_t*)(betab + (size_t)8192 * 16);   // bf16 [8192*128]
  ushort_t* gpreb = fpreb + (size_t)8192 * 128;
  ushort_t* wf1   = gpreb + (size_t)8192 * 128;               // [2048*128]
  ushort_t* wg1   = wf1 + (size_t)2048 * 128;
  ushort_t* wo    = wg1 + (size_t)2048 * 128;                 // [2048*2048]
  ushort_t* wlow  = wo + (size_t)2048 * 2048;                 // [384*2048]
  ushort_t* hb    = wlow + (size_t)384 * 2048;                // [BIG] bf16
  ushort_t* wqkv  = hb + BIG;                                 // [6144*2048] bf16
  // obuf (scan output, f32 BIG) aliases [hb | wqkv | pad] — all dead pre-scan
  float* obuf = (float*)hb;
  ushort_t* gatedb = (ushort_t*)qbuf;        // bf16 gated o (qbuf dead post-scan)

  const dim3 blk(256);

  // casts
  cast_bf16<<<16384, blk, 0, stream>>>(h, hb, 8192 * 2048);
  cast_bf16<<<4096, blk, 0, stream>>>(q_w, wqkv, 2048 * 2048);
  cast_bf16<<<4096, blk, 0, stream>>>(k_w, wqkv + (size_t)2048 * 2048, 2048 * 2048);
  cast_bf16<<<4096, blk, 0, stream>>>(v_w, wqkv + (size_t)4096 * 2048, 2048 * 2048);
  cast_bf16<<<4096, blk, 0, stream>>>(o_w, wo, 2048 * 2048);
  cast_bf16<<<256, blk, 0, stream>>>(f_w0, wlow, 128 * 2048);
  cast_bf16<<<256, blk, 0, stream>>>(g_w0, wlow + (size_t)128 * 2048, 128 * 2048);
  cast_bf16<<<32, blk, 0, stream>>>(b_w, wlow + (size_t)256 * 2048, 16 * 2048);
  cast_bf16<<<256, blk, 0, stream>>>(f_w1, wf1, 2048 * 128);
  cast_bf16<<<256, blk, 0, stream>>>(g_w1, wg1, 2048 * 128);

  // fused QKV projection: silu(+l2norm for q/k) -> qbuf/kbuf/vbuf f32
  gemm_bf16<<<dim3(48, 64), blk, 0, stream>>>(hb, wqkv, 8192, 6144, 2048, M_QKV,
      qbuf, kbuf, vbuf, nullptr, nullptr, nullptr, nullptr, nullptr);
  // fused lowrank: fpre|gpre (bf16) + beta (sigmoid f32)
  gemm_bf16<<<dim3(3, 64), blk, 0, stream>>>(hb, wlow, 8192, 384, 2048, M_LOWRANK,
      betab, nullptr, nullptr, fpreb, gpreb, nullptr, nullptr, nullptr);
  // exp(g) -> outp
  gemm_bf16<<<dim3(16, 64), blk, 0, stream>>>(fpreb, wf1, 8192, 2048, 128, M_GATE,
      outp, nullptr, nullptr, nullptr, nullptr, nullptr, A_log, dt_b);
  // scan: o -> obuf (hb/wqkv region dead), S -> d_out tail
  kda_scan<<<2048, 64, 0, stream>>>(qbuf, kbuf, vbuf, outp, betab, S0, obuf, Sout);
  // factor = gpre @ g_w1.T + g_b1 -> outp (exp(g) dead)
  gemm_bf16<<<dim3(16, 64), blk, 0, stream>>>(gpreb, wg1, 8192, 2048, 128, M_FACTOR,
      outp, nullptr, nullptr, nullptr, nullptr, g_b1, nullptr, nullptr);
  // gated rmsnorm -> bf16 into gatedb (qbuf region)
  gate_rmsnorm<<<2048, blk, 0, stream>>>(obuf, outp, o_nw, gatedb);
  // out = gated_o @ o_w.T -> outp
  gemm_bf16<<<dim3(16, 64), blk, 0, stream>>>(gatedb, wo, 8192, 2048, 2048, M_PLAIN,
      outp, nullptr, nullptr, nullptr, nullptr, nullptr, nullptr, nullptr);
}